// Round 5
// baseline (454.493 us; speedup 1.0000x reference)
//
#include <hip/hip_runtime.h>

// Chain of 9 Linear layers, no activation => collapse to one affine map.
// dims: 784 -> 69 -> 31 -> 10 -> ... -> 10
//
//   P1 (1 block):   S8 = W8*...*W1 [10,69], beff = S8 @ b0 + collapsed bias
//   P2 (31 blocks): Wt[j*10+o] = sum_k S8[o][k] * W0[k][j]   ([784][10], o fastest)
//   MAIN: out[b][o] = sum_j x[b][j]*Wt[j*10+o] + beff[o]
//
// MAIN (R5): coalesced x via wave-private LDS transpose.
//   R3==R4 proved the weight path irrelevant; the limiter is x divergence
//   (lane=row -> 64 cache lines per load instruction). Now: 4096 one-wave
//   blocks (rb 0..1023, q 0..3); wave stages 64rows x 28col chunks with
//   coalesced float4 loads (runs of 7 float4 per row), writes to LDS in a
//   rotation-swizzled layout pos(r,j)=r*32+4*((j+r)&7) so b128 writes AND
//   lane=row b128 reads are bank-balanced. Single 8KB buffer + register
//   prefetch of chunk c+1; in-wave DS ordering => ZERO barriers. 16 waves/CU.
//   Partials: atomicAdd into memset-zeroed out (bias folded into q==3).

__global__ void prep_collapse(
    const float* __restrict__ W1, const float* __restrict__ b1,
    const float* __restrict__ W2, const float* __restrict__ b2,
    const float* __restrict__ W3, const float* __restrict__ b3,
    const float* __restrict__ W4, const float* __restrict__ b4,
    const float* __restrict__ W5, const float* __restrict__ b5,
    const float* __restrict__ W6, const float* __restrict__ b6,
    const float* __restrict__ W7, const float* __restrict__ b7,
    const float* __restrict__ W8, const float* __restrict__ b8,
    const float* __restrict__ b0,
    float* __restrict__ S8out, float* __restrict__ beff)
{
    __shared__ float Sa[31 * 69], Sb[31 * 69];
    __shared__ float da[31], db[31];
    const int t = threadIdx.x;
    const int nt = blockDim.x;

    for (int i = t; i < 31 * 69; i += nt) Sa[i] = W1[i];
    for (int i = t; i < 31; i += nt) da[i] = b1[i];
    __syncthreads();

    for (int i = t; i < 10 * 69; i += nt) {
        int o = i / 69, c = i - o * 69;
        float s = 0.f;
        for (int k = 0; k < 31; k++) s += W2[o * 31 + k] * Sa[k * 69 + c];
        Sb[i] = s;
    }
    for (int i = t; i < 10; i += nt) {
        float s = b2[i];
        for (int k = 0; k < 31; k++) s += W2[i * 31 + k] * da[k];
        db[i] = s;
    }
    __syncthreads();

    const float* Wk[6] = { W3, W4, W5, W6, W7, W8 };
    const float* bk[6] = { b3, b4, b5, b6, b7, b8 };
    int src = 1;  // runtime ternaries: gfx950 rejects arrays of LDS pointers
    for (int st = 0; st < 6; st++) {
        const float* W = Wk[st];
        const float* bb = bk[st];
        float* S  = src ? Sb : Sa;
        float* D  = src ? Sa : Sb;
        float* dd = src ? db : da;
        float* dn = src ? da : db;
        for (int i = t; i < 10 * 69; i += nt) {
            int o = i / 69, c = i - o * 69;
            float s = 0.f;
            for (int k = 0; k < 10; k++) s += W[o * 10 + k] * S[k * 69 + c];
            D[i] = s;
        }
        for (int i = t; i < 10; i += nt) {
            float s = bb[i];
            for (int k = 0; k < 10; k++) s += W[i * 10 + k] * dd[k];
            dn[i] = s;
        }
        __syncthreads();
        src ^= 1;
    }

    float* S  = src ? Sb : Sa;
    float* dd = src ? db : da;
    for (int i = t; i < 690; i += nt) S8out[i] = S[i];
    for (int i = t; i < 10; i += nt) {
        float s = dd[i];
        for (int k = 0; k < 69; k++) s += S[i * 69 + k] * b0[k];
        beff[i] = s;
    }
}

__global__ void prep_fold0(const float* __restrict__ W0,
                           const float* __restrict__ S8,
                           float* __restrict__ Wt)
{
    int idx = blockIdx.x * blockDim.x + threadIdx.x;  // o*784 + j
    if (idx >= 7840) return;
    int o = idx / 784, j = idx - o * 784;
    float s = 0.f;
    for (int k = 0; k < 69; k++) s += S8[o * 69 + k] * W0[k * 784 + j];
    Wt[j * 10 + o] = s;  // [784][10]
}

// ---- main ----

__global__ __launch_bounds__(64, 4) void linear_main(
    const float* __restrict__ x, const float* __restrict__ Wt,
    const float* __restrict__ beff, float* __restrict__ out)
{
    __shared__ float xs[64 * 32];       // 8 KB: rotated float4 layout
    const int l  = threadIdx.x;         // lane = row within block (compute)
    const int rb = blockIdx.x >> 2;     // row-block 0..1023
    const int q  = blockIdx.x & 3;      // j-quarter 0..3
    const long row0 = (long)rb * 64;
    const float* xq = x + row0 * 784 + q * 196;
    const float* __restrict__ wq = Wt + q * 1960;   // wave-uniform -> s_load

    // staging index map: flat float4 g = i*64+l -> (row g/7, f4 g%7); lane-only
    int srow[7], sj[7];
#pragma unroll
    for (int i = 0; i < 7; i++) {
        int g = i * 64 + l;
        srow[i] = g / 7;                // magic-mul, computed once
        sj[i]   = g - 7 * srow[i];
    }

    float acc[10];
#pragma unroll
    for (int o = 0; o < 10; o++) acc[o] = 0.f;

    float4 pf[7];
    // chunk 0: load (coalesced runs of 7 float4/row) + swizzled LDS write
#pragma unroll
    for (int i = 0; i < 7; i++)
        pf[i] = *(const float4*)(xq + srow[i] * 784 + 4 * sj[i]);
#pragma unroll
    for (int i = 0; i < 7; i++)
        *(float4*)&xs[srow[i] * 32 + 4 * ((sj[i] + srow[i]) & 7)] = pf[i];

    for (int c = 0; c < 7; c++) {
        if (c < 6) {  // prefetch next chunk into registers (in flight over compute)
#pragma unroll
            for (int i = 0; i < 7; i++)
                pf[i] = *(const float4*)(xq + srow[i] * 784 + (c + 1) * 28 + 4 * sj[i]);
        }
        // compute chunk c: lane reads its own row, bank-balanced b128
        const float* wc = wq + c * 280;
#pragma unroll
        for (int j4 = 0; j4 < 7; j4++) {
            float4 xv = *(const float4*)&xs[l * 32 + 4 * ((j4 + l) & 7)];
            const float* w = wc + j4 * 40;
#pragma unroll
            for (int o = 0; o < 10; o++) acc[o] = fmaf(xv.x, w[o],      acc[o]);
#pragma unroll
            for (int o = 0; o < 10; o++) acc[o] = fmaf(xv.y, w[10 + o], acc[o]);
#pragma unroll
            for (int o = 0; o < 10; o++) acc[o] = fmaf(xv.z, w[20 + o], acc[o]);
#pragma unroll
            for (int o = 0; o < 10; o++) acc[o] = fmaf(xv.w, w[30 + o], acc[o]);
        }
        if (c < 6) {  // in-wave DS ordering: these writes can't pass the reads above
#pragma unroll
            for (int i = 0; i < 7; i++)
                *(float4*)&xs[srow[i] * 32 + 4 * ((sj[i] + srow[i]) & 7)] = pf[i];
        }
    }

    if (q == 3) {     // fold bias exactly once per row
#pragma unroll
        for (int o = 0; o < 10; o++) acc[o] += beff[o];
    }
    float* op = out + (row0 + l) * 10;
#pragma unroll
    for (int o = 0; o < 10; o++) atomicAdd(op + o, acc[o]);
}

extern "C" void kernel_launch(void* const* d_in, const int* in_sizes, int n_in,
                              void* d_out, int out_size, void* d_ws, size_t ws_size,
                              hipStream_t stream) {
    const float* x  = (const float*)d_in[0];
    const float* W0 = (const float*)d_in[1];
    const float* b0 = (const float*)d_in[2];
    const float* W1 = (const float*)d_in[3];
    const float* b1 = (const float*)d_in[4];
    const float* W2 = (const float*)d_in[5];
    const float* b2 = (const float*)d_in[6];
    const float* W3 = (const float*)d_in[7];
    const float* b3 = (const float*)d_in[8];
    const float* W4 = (const float*)d_in[9];
    const float* b4 = (const float*)d_in[10];
    const float* W5 = (const float*)d_in[11];
    const float* b5 = (const float*)d_in[12];
    const float* W6 = (const float*)d_in[13];
    const float* b6 = (const float*)d_in[14];
    const float* W7 = (const float*)d_in[15];
    const float* b7 = (const float*)d_in[16];
    const float* W8 = (const float*)d_in[17];
    const float* b8 = (const float*)d_in[18];

    float* ws   = (float*)d_ws;
    float* Wt   = ws;            // 7840 floats: [784][10]
    float* beff = ws + 7840;     // 10 floats
    float* S8   = ws + 7856;     // 690 floats

    float* out = (float*)d_out;
    const int B = in_sizes[0] / 784;  // 65536

    prep_collapse<<<1, 256, 0, stream>>>(W1, b1, W2, b2, W3, b3, W4, b4,
                                         W5, b5, W6, b6, W7, b7, W8, b8,
                                         b0, S8, beff);
    prep_fold0<<<31, 256, 0, stream>>>(W0, S8, Wt);
    // out accumulated by atomics -> zero it first (capture-legal async memset)
    hipMemsetAsync(out, 0, (size_t)out_size * sizeof(float), stream);
    linear_main<<<(B / 64) * 4, 64, 0, stream>>>(x, Wt, beff, out);
}

// Round 6
// 351.267 us; speedup vs baseline: 1.2939x; 1.2939x over previous
//
#include <hip/hip_runtime.h>

// Chain of 9 Linear layers, no activation => collapse to one affine map.
// dims: 784 -> 69 -> 31 -> 10 -> ... -> 10
//
//   P1 (1 block):   S8 = W8*...*W1 [10,69], beff = S8 @ b0 + collapsed bias
//   P2 (35 blocks): Wt2 padded layout, see below
//   MAIN: out[b][o] = sum_j x[b][j]*Wt[j][o] + beff[o]
//
// MAIN (R6): lane = (row, j-segment) — kills x divergence with NO transpose.
//   R3==R4 (~110us) proved x divergence (lane=row -> 64 lines/instr) is the
//   limiter; R5's atomics regressed (WRITE 271MB). Now: 512-thr blocks,
//   row = t>>3 (8 rows/wave), s = t&7 owns j = jb*32+s*4. x loads coalesced
//   (8 rows x 128B whole lines per instr). acc[10] per lane; 3-step shfl_xor
//   over the 8-lane row group at the end; lanes s<5 write float2. Weights
//   lane-dependent -> LDS, padded 11*float4 per j-quad: start bank quad
//   (3s+o)&7 -> all 8 addr groups disjoint, 8-way broadcast: conflict-free.
//   Tail 784=24*32+16: weight j4 196..199 zeroed, x addr clamped to 780.
//   LDS 35.2KB -> 4 blocks/CU = 32 waves/CU (max). No atomics, 1 barrier.

__global__ void prep_collapse(
    const float* __restrict__ W1, const float* __restrict__ b1,
    const float* __restrict__ W2, const float* __restrict__ b2,
    const float* __restrict__ W3, const float* __restrict__ b3,
    const float* __restrict__ W4, const float* __restrict__ b4,
    const float* __restrict__ W5, const float* __restrict__ b5,
    const float* __restrict__ W6, const float* __restrict__ b6,
    const float* __restrict__ W7, const float* __restrict__ b7,
    const float* __restrict__ W8, const float* __restrict__ b8,
    const float* __restrict__ b0,
    float* __restrict__ S8out, float* __restrict__ beff)
{
    __shared__ float Sa[31 * 69], Sb[31 * 69];
    __shared__ float da[31], db[31];
    const int t = threadIdx.x;
    const int nt = blockDim.x;

    for (int i = t; i < 31 * 69; i += nt) Sa[i] = W1[i];
    for (int i = t; i < 31; i += nt) da[i] = b1[i];
    __syncthreads();

    for (int i = t; i < 10 * 69; i += nt) {
        int o = i / 69, c = i - o * 69;
        float s = 0.f;
        for (int k = 0; k < 31; k++) s += W2[o * 31 + k] * Sa[k * 69 + c];
        Sb[i] = s;
    }
    for (int i = t; i < 10; i += nt) {
        float s = b2[i];
        for (int k = 0; k < 31; k++) s += W2[i * 31 + k] * da[k];
        db[i] = s;
    }
    __syncthreads();

    const float* Wk[6] = { W3, W4, W5, W6, W7, W8 };
    const float* bk[6] = { b3, b4, b5, b6, b7, b8 };
    int src = 1;  // runtime ternaries: gfx950 rejects arrays of LDS pointers
    for (int st = 0; st < 6; st++) {
        const float* W = Wk[st];
        const float* bb = bk[st];
        float* S  = src ? Sb : Sa;
        float* D  = src ? Sa : Sb;
        float* dd = src ? db : da;
        float* dn = src ? da : db;
        for (int i = t; i < 10 * 69; i += nt) {
            int o = i / 69, c = i - o * 69;
            float s = 0.f;
            for (int k = 0; k < 10; k++) s += W[o * 10 + k] * S[k * 69 + c];
            D[i] = s;
        }
        for (int i = t; i < 10; i += nt) {
            float s = bb[i];
            for (int k = 0; k < 10; k++) s += W[i * 10 + k] * dd[k];
            dn[i] = s;
        }
        __syncthreads();
        src ^= 1;
    }

    float* S  = src ? Sb : Sa;
    float* dd = src ? db : da;
    for (int i = t; i < 690; i += nt) S8out[i] = S[i];
    for (int i = t; i < 10; i += nt) {
        float s = dd[i];
        for (int k = 0; k < 69; k++) s += S[i * 69 + k] * b0[k];
        beff[i] = s;
    }
}

// Wt2 layout: [200 j-quads][11 float4]; entry (j4, o<10) = {W[o][j4*4+k]}_{k=0..3}
// (composed weight); o==10 and j4 in [196,200) are zero padding.
__global__ void prep_fold0(const float* __restrict__ W0,
                           const float* __restrict__ S8,
                           float* __restrict__ Wt2)
{
    int idx = blockIdx.x * blockDim.x + threadIdx.x;  // 0..8799
    if (idx >= 8800) return;
    int j4 = idx / 44, rem = idx - j4 * 44;
    float val = 0.f;
    if (rem < 40) {
        int o = rem >> 2, k = rem & 3, j = j4 * 4 + k;
        if (j < 784) {
            for (int u = 0; u < 69; u++) val += S8[o * 69 + u] * W0[u * 784 + j];
        }
    }
    Wt2[idx] = val;
}

// ---- main ----

__global__ __launch_bounds__(512, 8) void linear_main(
    const float* __restrict__ x, const float* __restrict__ Wt2,
    const float* __restrict__ beff, float* __restrict__ out)
{
    __shared__ float4 wlds[2200];   // 35.2 KB
    const int t = threadIdx.x;
    const int s = t & 7;                         // j-segment within row group
    const long row = (long)blockIdx.x * 64 + (t >> 3);
    const float* xrow = x + row * 784;

    // stage weights (independent of the first x load)
    {
        const float4* wg = (const float4*)Wt2;
        for (int i = t; i < 2200; i += 512) wlds[i] = wg[i];
    }

    float acc[10];
#pragma unroll
    for (int o = 0; o < 10; o++) acc[o] = 0.f;

    // first x load issued before the barrier
    float4 xv = *(const float4*)(xrow + s * 4);
    __syncthreads();

    for (int jb = 0; jb < 25; jb++) {
        float4 xc = xv;
        if (jb < 24) {
            int jn = (jb + 1) * 32 + s * 4;
            jn = jn > 780 ? 780 : jn;            // clamp: tail cols have zero W
            xv = *(const float4*)(xrow + jn);
        }
        const float4* wrow = &wlds[(jb * 8 + s) * 11];
#pragma unroll
        for (int o = 0; o < 10; o++) {
            float4 wv = wrow[o];
            acc[o] = fmaf(xc.x, wv.x, acc[o]);
            acc[o] = fmaf(xc.y, wv.y, acc[o]);
            acc[o] = fmaf(xc.z, wv.z, acc[o]);
            acc[o] = fmaf(xc.w, wv.w, acc[o]);
        }
    }

    // butterfly sum over the 8 lanes sharing this row (bits 0..2 of lane id)
#pragma unroll
    for (int m = 1; m < 8; m <<= 1)
#pragma unroll
        for (int o = 0; o < 10; o++) acc[o] += __shfl_xor(acc[o], m, 64);

    // lanes s<5 write float2 (out + row*10 is 8B-aligned; 40B per row)
    if (s < 5) {
        float lo = 0.f, hi = 0.f;
#pragma unroll
        for (int o = 0; o < 5; o++) {
            if (s == o) { lo = acc[2 * o]; hi = acc[2 * o + 1]; }  // cndmask chain
        }
        lo += beff[s * 2];
        hi += beff[s * 2 + 1];
        *(float2*)(out + row * 10 + s * 2) = make_float2(lo, hi);
    }
}

extern "C" void kernel_launch(void* const* d_in, const int* in_sizes, int n_in,
                              void* d_out, int out_size, void* d_ws, size_t ws_size,
                              hipStream_t stream) {
    const float* x  = (const float*)d_in[0];
    const float* W0 = (const float*)d_in[1];
    const float* b0 = (const float*)d_in[2];
    const float* W1 = (const float*)d_in[3];
    const float* b1 = (const float*)d_in[4];
    const float* W2 = (const float*)d_in[5];
    const float* b2 = (const float*)d_in[6];
    const float* W3 = (const float*)d_in[7];
    const float* b3 = (const float*)d_in[8];
    const float* W4 = (const float*)d_in[9];
    const float* b4 = (const float*)d_in[10];
    const float* W5 = (const float*)d_in[11];
    const float* b5 = (const float*)d_in[12];
    const float* W6 = (const float*)d_in[13];
    const float* b6 = (const float*)d_in[14];
    const float* W7 = (const float*)d_in[15];
    const float* b7 = (const float*)d_in[16];
    const float* W8 = (const float*)d_in[17];
    const float* b8 = (const float*)d_in[18];

    float* ws   = (float*)d_ws;
    float* Wt2  = ws;            // 8800 floats: [200 j4][11 float4]
    float* beff = ws + 8800;     // 10 floats
    float* S8   = ws + 8816;     // 690 floats

    float* out = (float*)d_out;
    const int B = in_sizes[0] / 784;  // 65536

    prep_collapse<<<1, 256, 0, stream>>>(W1, b1, W2, b2, W3, b3, W4, b4,
                                         W5, b5, W6, b6, W7, b7, W8, b8,
                                         b0, S8, beff);
    prep_fold0<<<35, 256, 0, stream>>>(W0, S8, Wt2);
    linear_main<<<B / 64, 512, 0, stream>>>(x, Wt2, beff, out);
}